// Round 1
// baseline (343.646 us; speedup 1.0000x reference)
//
#include <hip/hip_runtime.h>

typedef unsigned short ushort_t;
typedef unsigned int uint_t;

using bf16x8 = __attribute__((ext_vector_type(8))) short;
using f32x4  = __attribute__((ext_vector_type(4))) float;

// ---------- helpers ----------
__device__ __forceinline__ ushort_t f2b(float f){
    union { float f; uint_t u; } v; v.f = f;
    uint_t u = v.u;
    uint_t r = (u + 0x7FFFu + ((u >> 16) & 1u)) >> 16;   // RNE
    return (ushort_t)r;
}
__device__ __forceinline__ float sig_(float x){
    return __builtin_amdgcn_rcpf(1.f + __builtin_amdgcn_exp2f(-1.44269504f * x));
}
__device__ __forceinline__ float tanh_(float x){
    return 1.f - 2.f * __builtin_amdgcn_rcpf(1.f + __builtin_amdgcn_exp2f(2.88539008f * x));
}

// ---------- weight prep: f32 -> bf16 (+ conv restride) ----------
__global__ void prep_k(const float* __restrict__ vW, const float* __restrict__ Wx,
                       const float* __restrict__ Wh, const float* __restrict__ cW,
                       const float* __restrict__ sW, const float* __restrict__ oW,
                       const float* __restrict__ pW, ushort_t* __restrict__ wb)
{
    int idx = blockIdx.x * 256 + threadIdx.x;
    switch (blockIdx.y){
    case 0: if (idx < 16384) wb[idx]          = f2b(vW[idx]);           break;
    case 1: if (idx < 65536) wb[16384  + idx] = f2b(Wx[idx]);           break; // Wx0
    case 2: if (idx < 65536) wb[81920  + idx] = f2b(Wh[idx]);           break; // Wh0
    case 3: if (idx < 65536) wb[147456 + idx] = f2b(Wx[65536 + idx]);   break; // Wx1
    case 4: if (idx < 65536) wb[212992 + idx] = f2b(Wh[65536 + idx]);   break; // Wh1
    case 5: if (idx < 49152){                                                  // conv [k][o][i]
                int k = idx >> 14; int oi = idx & 16383;
                wb[278528 + idx] = f2b(cW[oi * 3 + k]);
            } break;
    case 6: if (idx < 16384) wb[327680 + idx] = f2b(sW[idx]);           break;
    case 7: if (idx < 16384) wb[344064 + idx] = f2b(oW[idx]);           break;
    case 8: if (idx < 12288) wb[360448 + idx] = f2b(pW[idx]);           break;
    }
}

// ---------- patch embed + layernorm ----------
// grid 672 (one per bc), block 128 (thread = output channel e)
__global__ void embed_ln_k(const float* __restrict__ x, const float* __restrict__ eW,
                           const float* __restrict__ eb, const float* __restrict__ lng,
                           const float* __restrict__ lnb,
                           float* __restrict__ xnF, ushort_t* __restrict__ xnB)
{
    const int e  = threadIdx.x;
    const int bc = blockIdx.x;
    const int b  = bc / 21, c = bc % 21;
    const int wid = threadIdx.x >> 6;

    float w[16];
#pragma unroll
    for (int p = 0; p < 16; ++p) w[p] = eW[e * 16 + p];
    const float bias = eb[e], gam = lng[e], bet = lnb[e];

    __shared__ float patch[16];
    __shared__ float red[4];

    for (int n = 0; n < 8; ++n){
        if (e < 16) patch[e] = x[(b * 128 + n * 16 + e) * 21 + c];
        __syncthreads();
        float v = bias;
#pragma unroll
        for (int p = 0; p < 16; ++p) v += w[p] * patch[p];

        float s = v, sq = v * v;
#pragma unroll
        for (int m = 32; m >= 1; m >>= 1){
            s  += __shfl_xor(s,  m);
            sq += __shfl_xor(sq, m);
        }
        if ((threadIdx.x & 63) == 0){ red[wid] = s; red[2 + wid] = sq; }
        __syncthreads();
        float S  = red[0] + red[1];
        float SQ = red[2] + red[3];
        float mean = S * (1.f / 128.f);
        float var  = SQ * (1.f / 128.f) - mean * mean;
        float r    = rsqrtf(var + 1e-5f);
        float y    = (v - mean) * r * gam + bet;
        int row = bc * 8 + n;
        xnF[row * 128 + e] = y;
        xnB[row * 128 + e] = f2b(y);
        __syncthreads();
    }
}

// ---------- generic MFMA matmul: Y(5376 x OUT) = A(5376x128) @ W(OUTx128)^T + bias ----------
// grid 84, block 256 (4 waves, wave = 16-row tile)
__global__ void mm16_k(const ushort_t* __restrict__ A, const ushort_t* __restrict__ W,
                       const float* __restrict__ bias, const float* __restrict__ resid,
                       float* __restrict__ outF, ushort_t* __restrict__ outB, int OUT)
{
    const int lane = threadIdx.x & 63, wave = threadIdx.x >> 6;
    const int rowbase = blockIdx.x * 64 + wave * 16;
    const int r0 = lane & 15, g = lane >> 4;

    bf16x8 a[4];
    const ushort_t* ap = A + (rowbase + r0) * 128 + g * 8;
#pragma unroll
    for (int kt = 0; kt < 4; ++kt) a[kt] = *(const bf16x8*)(ap + kt * 32);

    const int ntiles = OUT >> 4;
    for (int nt = 0; nt < ntiles; ++nt){
        const int col = nt * 16 + r0;
        float bv = bias[col];
        f32x4 acc = {bv, bv, bv, bv};
        const ushort_t* wp = W + col * 128 + g * 8;
#pragma unroll
        for (int kt = 0; kt < 4; ++kt)
            acc = __builtin_amdgcn_mfma_f32_16x16x32_bf16(a[kt], *(const bf16x8*)(wp + kt * 32), acc, 0, 0, 0);
#pragma unroll
        for (int q = 0; q < 4; ++q){
            int row = rowbase + g * 4 + q;
            float val = acc[q];
            if (resid) val += resid[row * 128 + col];
            if (outF)  outF[row * OUT + col] = val;
            if (outB)  outB[row * OUT + col] = f2b(val);
        }
    }
}

// ---------- conv1d SAME (K=3) as 3 shifted matmuls ----------
__global__ void conv16_k(const ushort_t* __restrict__ A, const ushort_t* __restrict__ Wk,
                         const float* __restrict__ bias, ushort_t* __restrict__ outB)
{
    const int lane = threadIdx.x & 63, wave = threadIdx.x >> 6;
    const int rowbase = blockIdx.x * 64 + wave * 16;
    const int r0 = lane & 15, g = lane >> 4;
    const int n = r0 & 7;

    bf16x8 a[3][4];
#pragma unroll
    for (int k = 0; k < 3; ++k){
        bool valid = (n + k >= 1) && (n + k <= 8);
        const ushort_t* ap = A + (rowbase + r0 + k - 1) * 128 + g * 8;
#pragma unroll
        for (int kt = 0; kt < 4; ++kt){
            bf16x8 z = {0,0,0,0,0,0,0,0};
            a[k][kt] = valid ? *(const bf16x8*)(ap + kt * 32) : z;
        }
    }
    for (int nt = 0; nt < 8; ++nt){
        const int col = nt * 16 + r0;
        float bv = bias[col];
        f32x4 acc = {bv, bv, bv, bv};
#pragma unroll
        for (int k = 0; k < 3; ++k)
#pragma unroll
            for (int kt = 0; kt < 4; ++kt)
                acc = __builtin_amdgcn_mfma_f32_16x16x32_bf16(
                        a[k][kt],
                        *(const bf16x8*)(Wk + k * 16384 + col * 128 + kt * 32 + g * 8),
                        acc, 0, 0, 0);
#pragma unroll
        for (int q = 0; q < 4; ++q){
            int row = rowbase + g * 4 + q;
            outB[row * 128 + col] = f2b(acc[q]);
        }
    }
}

// ---------- persistent 2-layer LSTM, 64 sequential steps ----------
// grid 42, block 512 (8 waves). 16 batch rows per block.
// Wave w owns gate columns {16w..16w+15} of each of i/f/g/o blocks.
__global__ __launch_bounds__(512, 2) void lstm_k(
    const float* __restrict__ X0, const ushort_t* __restrict__ Wh0,
    const ushort_t* __restrict__ Wx1, const ushort_t* __restrict__ Wh1,
    const float* __restrict__ lb, ushort_t* __restrict__ outB)
{
    __shared__ ushort_t h0[2][2048];
    __shared__ ushort_t h1[2][2048];

    const int tid  = threadIdx.x;
    const int wid  = tid >> 6, lane = tid & 63;
    const int r0   = lane & 15, g = lane >> 4;
    const int bcb  = blockIdx.x * 16;

    for (int i = tid; i < 2048; i += 512){
        h0[0][i] = 0; h0[1][i] = 0; h1[0][i] = 0; h1[1][i] = 0;
    }

    int cb[4];
#pragma unroll
    for (int t4 = 0; t4 < 4; ++t4) cb[t4] = t4 * 128 + wid * 16;

    bf16x8 wh0[4][4], wh1[4][4];
#pragma unroll
    for (int t4 = 0; t4 < 4; ++t4)
#pragma unroll
        for (int kt = 0; kt < 4; ++kt){
            wh0[t4][kt] = *(const bf16x8*)(Wh0 + (cb[t4] + r0) * 128 + kt * 32 + g * 8);
            wh1[t4][kt] = *(const bf16x8*)(Wh1 + (cb[t4] + r0) * 128 + kt * 32 + g * 8);
        }
    float b1v[4];
#pragma unroll
    for (int t4 = 0; t4 < 4; ++t4) b1v[t4] = lb[512 + cb[t4] + r0];

    int baseq[4];
#pragma unroll
    for (int q = 0; q < 4; ++q) baseq[q] = (bcb + g * 4 + q) * 4096 + r0;

    float c0[4] = {0,0,0,0}, c1[4] = {0,0,0,0};

    float xb[4][4];
#pragma unroll
    for (int t4 = 0; t4 < 4; ++t4)
#pragma unroll
        for (int q = 0; q < 4; ++q) xb[t4][q] = X0[baseq[q] + cb[t4]];   // t = 0

    __syncthreads();

    for (int step = 0; step < 64; ++step){
        const int t = step & 7, p = step & 1;

        // ---- phase A: layer 0 ----
        bf16x8 a0[4];
#pragma unroll
        for (int kt = 0; kt < 4; ++kt)
            a0[kt] = *(const bf16x8*)(&h0[p][ r0 * 128 + ((kt * 32 + g * 8) ^ ((r0 & 7) << 3)) ]);

        f32x4 acc[4];
#pragma unroll
        for (int t4 = 0; t4 < 4; ++t4){
            f32x4 tmp = {xb[t4][0], xb[t4][1], xb[t4][2], xb[t4][3]};
            acc[t4] = tmp;
        }
#pragma unroll
        for (int t4 = 0; t4 < 4; ++t4)
#pragma unroll
            for (int kt = 0; kt < 4; ++kt)
                acc[t4] = __builtin_amdgcn_mfma_f32_16x16x32_bf16(a0[kt], wh0[t4][kt], acc[t4], 0, 0, 0);

#pragma unroll
        for (int q = 0; q < 4; ++q){
            float iv = acc[0][q], fv = acc[1][q], gv = acc[2][q], ov = acc[3][q];
            float cn = sig_(fv) * c0[q] + sig_(iv) * tanh_(gv);
            c0[q] = cn;
            float hv = sig_(ov) * tanh_(cn);
            int row = g * 4 + q;
            h0[p ^ 1][ row * 128 + ((wid * 16 + r0) ^ ((row & 7) << 3)) ] = f2b(hv);
        }
        __syncthreads();   // B1: h0[p^1] visible

        // ---- phase B: layer 1 ----
        bf16x8 a1x[4], a1h[4];
#pragma unroll
        for (int kt = 0; kt < 4; ++kt){
            int off = (kt * 32 + g * 8) ^ ((r0 & 7) << 3);
            a1x[kt] = *(const bf16x8*)(&h0[p ^ 1][ r0 * 128 + off ]);
            a1h[kt] = *(const bf16x8*)(&h1[p    ][ r0 * 128 + off ]);
        }
#pragma unroll
        for (int t4 = 0; t4 < 4; ++t4){
            f32x4 tmp = {b1v[t4], b1v[t4], b1v[t4], b1v[t4]};
            acc[t4] = tmp;
        }
#pragma unroll
        for (int t4 = 0; t4 < 4; ++t4){
#pragma unroll
            for (int kt = 0; kt < 4; ++kt){
                bf16x8 bx = *(const bf16x8*)(Wx1 + (cb[t4] + r0) * 128 + kt * 32 + g * 8);
                acc[t4] = __builtin_amdgcn_mfma_f32_16x16x32_bf16(a1x[kt], bx,          acc[t4], 0, 0, 0);
                acc[t4] = __builtin_amdgcn_mfma_f32_16x16x32_bf16(a1h[kt], wh1[t4][kt], acc[t4], 0, 0, 0);
            }
        }

        // prefetch X0 for next step (overlaps EW below until the barrier)
        if (step < 63){
            const int tn = (step + 1) & 7;
#pragma unroll
            for (int t4 = 0; t4 < 4; ++t4)
#pragma unroll
                for (int q = 0; q < 4; ++q)
                    xb[t4][q] = X0[baseq[q] + tn * 512 + cb[t4]];
        }

#pragma unroll
        for (int q = 0; q < 4; ++q){
            float iv = acc[0][q], fv = acc[1][q], gv = acc[2][q], ov = acc[3][q];
            float cn = sig_(fv) * c1[q] + sig_(iv) * tanh_(gv);
            c1[q] = cn;
            float hv = sig_(ov) * tanh_(cn);
            int row = g * 4 + q;
            h1[p ^ 1][ row * 128 + ((wid * 16 + r0) ^ ((row & 7) << 3)) ] = f2b(hv);
            if (step >= 56)
                outB[ ((bcb + row) * 8 + t) * 128 + wid * 16 + r0 ] = f2b(hv);
        }
        __syncthreads();   // B2: end of step
    }
}

// ---------- launch ----------
extern "C" void kernel_launch(void* const* d_in, const int* in_sizes, int n_in,
                              void* d_out, int out_size, void* d_ws, size_t ws_size,
                              hipStream_t stream)
{
    const float* x   = (const float*)d_in[0];
    const float* eW  = (const float*)d_in[1];
    const float* eb  = (const float*)d_in[2];
    const float* lng = (const float*)d_in[3];
    const float* lnb = (const float*)d_in[4];
    const float* vW  = (const float*)d_in[9];
    const float* vb  = (const float*)d_in[10];
    const float* Wx  = (const float*)d_in[11];
    const float* Wh  = (const float*)d_in[12];
    const float* lb  = (const float*)d_in[13];
    const float* cW  = (const float*)d_in[14];
    const float* cb_ = (const float*)d_in[15];
    const float* sW  = (const float*)d_in[16];
    const float* sb  = (const float*)d_in[17];
    const float* oW  = (const float*)d_in[18];
    const float* ob  = (const float*)d_in[19];
    const float* pW  = (const float*)d_in[20];
    const float* pb  = (const float*)d_in[21];

    char* ws = (char*)d_ws;
    float*    xnF = (float*)   (ws + 0);          // 5376x128 f32
    ushort_t* xnB = (ushort_t*)(ws + 2752512);    // 5376x128 bf16
    ushort_t* c0B = (ushort_t*)(ws + 4128768);    // ctx0 bf16
    float*    X0F = (float*)   (ws + 5505024);    // 5376x512 f32
    ushort_t* lsB = (ushort_t*)(ws + 16515072);   // lstm out bf16
    ushort_t* cvB = (ushort_t*)(ws + 17891328);   // conv out bf16
    ushort_t* ssB = (ushort_t*)(ws + 19267584);   // ssm out bf16
    ushort_t* cpB = (ushort_t*)(ws + 20643840);   // (outp + xn) bf16
    ushort_t* wb  = (ushort_t*)(ws + 22020096);   // bf16 weights

    prep_k<<<dim3(256, 9), 256, 0, stream>>>(vW, Wx, Wh, cW, sW, oW, pW, wb);
    embed_ln_k<<<672, 128, 0, stream>>>(x, eW, eb, lng, lnb, xnF, xnB);
    // ctx0 = xn @ vW^T + vb   (attention collapses to identity on v)
    mm16_k<<<84, 256, 0, stream>>>(xnB, wb + 0,      vb, nullptr, nullptr, c0B, 128);
    // X0 = ctx0 @ Wx0^T + b0
    mm16_k<<<84, 256, 0, stream>>>(c0B, wb + 16384,  lb, nullptr, X0F,     nullptr, 512);
    lstm_k<<<42, 512, 0, stream>>>(X0F, wb + 81920, wb + 147456, wb + 212992, lb, lsB);
    conv16_k<<<84, 256, 0, stream>>>(lsB, wb + 278528, cb_, cvB);
    mm16_k<<<84, 256, 0, stream>>>(cvB, wb + 327680, sb, nullptr, nullptr, ssB, 128);
    mm16_k<<<84, 256, 0, stream>>>(ssB, wb + 344064, ob, xnF,    nullptr, cpB, 128);
    mm16_k<<<84, 256, 0, stream>>>(cpB, wb + 360448, pb, nullptr, (float*)d_out, nullptr, 96);
}

// Round 2
// 304.654 us; speedup vs baseline: 1.1280x; 1.1280x over previous
//
#include <hip/hip_runtime.h>

typedef unsigned short ushort_t;
typedef unsigned int uint_t;

using bf16x8 = __attribute__((ext_vector_type(8))) short;
using f32x4  = __attribute__((ext_vector_type(4))) float;

// ---------- helpers ----------
__device__ __forceinline__ ushort_t f2b(float f){
    union { float f; uint_t u; } v; v.f = f;
    uint_t u = v.u;
    uint_t r = (u + 0x7FFFu + ((u >> 16) & 1u)) >> 16;   // RNE
    return (ushort_t)r;
}
__device__ __forceinline__ float sig_(float x){
    return __builtin_amdgcn_rcpf(1.f + __builtin_amdgcn_exp2f(-1.44269504f * x));
}
__device__ __forceinline__ float tanh_(float x){
    return 1.f - 2.f * __builtin_amdgcn_rcpf(1.f + __builtin_amdgcn_exp2f(2.88539008f * x));
}

// ---------- weight prep: f32 -> bf16 (+ conv restride) ----------
__global__ void prep_k(const float* __restrict__ vW, const float* __restrict__ Wx,
                       const float* __restrict__ Wh, const float* __restrict__ cW,
                       const float* __restrict__ sW, const float* __restrict__ oW,
                       const float* __restrict__ pW, ushort_t* __restrict__ wb)
{
    int idx = blockIdx.x * 256 + threadIdx.x;
    switch (blockIdx.y){
    case 0: if (idx < 16384) wb[idx]          = f2b(vW[idx]);           break;
    case 1: if (idx < 65536) wb[16384  + idx] = f2b(Wx[idx]);           break; // Wx0
    case 2: if (idx < 65536) wb[81920  + idx] = f2b(Wh[idx]);           break; // Wh0
    case 3: if (idx < 65536) wb[147456 + idx] = f2b(Wx[65536 + idx]);   break; // Wx1
    case 4: if (idx < 65536) wb[212992 + idx] = f2b(Wh[65536 + idx]);   break; // Wh1
    case 5: if (idx < 49152){                                                  // conv [k][o][i]
                int k = idx >> 14; int oi = idx & 16383;
                wb[278528 + idx] = f2b(cW[oi * 3 + k]);
            } break;
    case 6: if (idx < 16384) wb[327680 + idx] = f2b(sW[idx]);           break;
    case 7: if (idx < 16384) wb[344064 + idx] = f2b(oW[idx]);           break;
    case 8: if (idx < 12288) wb[360448 + idx] = f2b(pW[idx]);           break;
    }
}

// ---------- patch embed + layernorm ----------
__global__ void embed_ln_k(const float* __restrict__ x, const float* __restrict__ eW,
                           const float* __restrict__ eb, const float* __restrict__ lng,
                           const float* __restrict__ lnb,
                           float* __restrict__ xnF, ushort_t* __restrict__ xnB)
{
    const int e  = threadIdx.x;
    const int bc = blockIdx.x;
    const int b  = bc / 21, c = bc % 21;
    const int wid = threadIdx.x >> 6;

    float w[16];
#pragma unroll
    for (int p = 0; p < 16; ++p) w[p] = eW[e * 16 + p];
    const float bias = eb[e], gam = lng[e], bet = lnb[e];

    __shared__ float patch[16];
    __shared__ float red[4];

    for (int n = 0; n < 8; ++n){
        if (e < 16) patch[e] = x[(b * 128 + n * 16 + e) * 21 + c];
        __syncthreads();
        float v = bias;
#pragma unroll
        for (int p = 0; p < 16; ++p) v += w[p] * patch[p];

        float s = v, sq = v * v;
#pragma unroll
        for (int m = 32; m >= 1; m >>= 1){
            s  += __shfl_xor(s,  m);
            sq += __shfl_xor(sq, m);
        }
        if ((threadIdx.x & 63) == 0){ red[wid] = s; red[2 + wid] = sq; }
        __syncthreads();
        float S  = red[0] + red[1];
        float SQ = red[2] + red[3];
        float mean = S * (1.f / 128.f);
        float var  = SQ * (1.f / 128.f) - mean * mean;
        float r    = rsqrtf(var + 1e-5f);
        float y    = (v - mean) * r * gam + bet;
        int row = bc * 8 + n;
        xnF[row * 128 + e] = y;
        xnB[row * 128 + e] = f2b(y);
        __syncthreads();
    }
}

// ---------- generic MFMA matmul: Y(5376 x OUT) = A(5376x128) @ W(OUTx128)^T + bias ----------
__global__ void mm16_k(const ushort_t* __restrict__ A, const ushort_t* __restrict__ W,
                       const float* __restrict__ bias, const float* __restrict__ resid,
                       float* __restrict__ outF, ushort_t* __restrict__ outB, int OUT)
{
    const int lane = threadIdx.x & 63, wave = threadIdx.x >> 6;
    const int rowbase = blockIdx.x * 64 + wave * 16;
    const int r0 = lane & 15, g = lane >> 4;

    bf16x8 a[4];
    const ushort_t* ap = A + (rowbase + r0) * 128 + g * 8;
#pragma unroll
    for (int kt = 0; kt < 4; ++kt) a[kt] = *(const bf16x8*)(ap + kt * 32);

    const int ntiles = OUT >> 4;
    for (int nt = 0; nt < ntiles; ++nt){
        const int col = nt * 16 + r0;
        float bv = bias[col];
        f32x4 acc = {bv, bv, bv, bv};
        const ushort_t* wp = W + col * 128 + g * 8;
#pragma unroll
        for (int kt = 0; kt < 4; ++kt)
            acc = __builtin_amdgcn_mfma_f32_16x16x32_bf16(a[kt], *(const bf16x8*)(wp + kt * 32), acc, 0, 0, 0);
#pragma unroll
        for (int q = 0; q < 4; ++q){
            int row = rowbase + g * 4 + q;
            float val = acc[q];
            if (resid) val += resid[row * 128 + col];
            if (outF)  outF[row * OUT + col] = val;
            if (outB)  outB[row * OUT + col] = f2b(val);
        }
    }
}

// ---------- persistent 2-layer LSTM, 64 sequential steps ----------
// grid 42, block 512 (8 waves). 16 batch rows per block.
// ALL weights (Wh0, Wx1, Wh1) live in registers (192 VGPR/wave);
// X0 prefetched directly into the phase-A accumulator; ONE barrier per step.
__global__ __launch_bounds__(512, 2) void lstm_k(
    const float* __restrict__ X0, const ushort_t* __restrict__ Wh0,
    const ushort_t* __restrict__ Wx1, const ushort_t* __restrict__ Wh1,
    const float* __restrict__ lb, ushort_t* __restrict__ outB)
{
    __shared__ ushort_t h0[2][2048];
    __shared__ ushort_t h1[2][2048];

    const int tid  = threadIdx.x;
    const int wid  = tid >> 6, lane = tid & 63;
    const int r0   = lane & 15, g = lane >> 4;
    const int bcb  = blockIdx.x * 16;

    for (int i = tid; i < 2048; i += 512){
        h0[0][i] = 0; h0[1][i] = 0; h1[0][i] = 0; h1[1][i] = 0;
    }

    bf16x8 wh0[4][4], wh1[4][4], wx1r[4][4];
#pragma unroll
    for (int t4 = 0; t4 < 4; ++t4){
        const int cb = t4 * 128 + wid * 16;
#pragma unroll
        for (int kt = 0; kt < 4; ++kt){
            wh0[t4][kt]  = *(const bf16x8*)(Wh0 + (cb + r0) * 128 + kt * 32 + g * 8);
            wh1[t4][kt]  = *(const bf16x8*)(Wh1 + (cb + r0) * 128 + kt * 32 + g * 8);
            wx1r[t4][kt] = *(const bf16x8*)(Wx1 + (cb + r0) * 128 + kt * 32 + g * 8);
        }
    }
    float b1v[4];
#pragma unroll
    for (int t4 = 0; t4 < 4; ++t4) b1v[t4] = lb[512 + t4 * 128 + wid * 16 + r0];

    float c0[4] = {0,0,0,0}, c1[4] = {0,0,0,0};

    // acc doubles as the X0/gate-0 pre-initialized accumulator
    f32x4 acc[4];
#pragma unroll
    for (int t4 = 0; t4 < 4; ++t4)
#pragma unroll
        for (int q = 0; q < 4; ++q)
            acc[t4][q] = X0[(bcb + g * 4 + q) * 4096 + t4 * 128 + wid * 16 + r0];

    __syncthreads();

    for (int step = 0; step < 64; ++step){
        const int p = step & 1;

        // ---- phase A: layer 0 (acc pre-loaded with X0 slice = Wx0 part + bias) ----
#pragma unroll
        for (int kt = 0; kt < 4; ++kt){
            bf16x8 a0 = *(const bf16x8*)(&h0[p][ r0 * 128 + ((kt * 32 + g * 8) ^ ((r0 & 7) << 3)) ]);
#pragma unroll
            for (int t4 = 0; t4 < 4; ++t4)
                acc[t4] = __builtin_amdgcn_mfma_f32_16x16x32_bf16(a0, wh0[t4][kt], acc[t4], 0, 0, 0);
        }
#pragma unroll
        for (int q = 0; q < 4; ++q){
            float iv = acc[0][q], fv = acc[1][q], gv = acc[2][q], ov = acc[3][q];
            float cn = sig_(fv) * c0[q] + sig_(iv) * tanh_(gv);
            c0[q] = cn;
            float hv = sig_(ov) * tanh_(cn);
            int row = g * 4 + q;
            h0[p ^ 1][ row * 128 + ((wid * 16 + r0) ^ ((row & 7) << 3)) ] = f2b(hv);
        }
        __syncthreads();   // the ONE barrier per step

        // ---- phase B: layer 1 ----
#pragma unroll
        for (int t4 = 0; t4 < 4; ++t4){
            f32x4 tmp = {b1v[t4], b1v[t4], b1v[t4], b1v[t4]};
            acc[t4] = tmp;
        }
#pragma unroll
        for (int kt = 0; kt < 4; ++kt){
            const int off = (kt * 32 + g * 8) ^ ((r0 & 7) << 3);
            bf16x8 ax = *(const bf16x8*)(&h0[p ^ 1][ r0 * 128 + off ]);
            bf16x8 ah = *(const bf16x8*)(&h1[p    ][ r0 * 128 + off ]);
#pragma unroll
            for (int t4 = 0; t4 < 4; ++t4){
                acc[t4] = __builtin_amdgcn_mfma_f32_16x16x32_bf16(ax, wx1r[t4][kt], acc[t4], 0, 0, 0);
                acc[t4] = __builtin_amdgcn_mfma_f32_16x16x32_bf16(ah, wh1[t4][kt], acc[t4], 0, 0, 0);
            }
        }

#pragma unroll
        for (int q = 0; q < 4; ++q){
            float iv = acc[0][q], fv = acc[1][q], gv = acc[2][q], ov = acc[3][q];
            float cn = sig_(fv) * c1[q] + sig_(iv) * tanh_(gv);
            c1[q] = cn;
            float hv = sig_(ov) * tanh_(cn);
            int row = g * 4 + q;
            h1[p ^ 1][ row * 128 + ((wid * 16 + r0) ^ ((row & 7) << 3)) ] = f2b(hv);
            if (step >= 56)
                outB[ ((bcb + row) * 8 + (step & 7)) * 128 + wid * 16 + r0 ] = f2b(hv);
        }

        // prefetch next step's X0 slice straight into acc (phase-A init)
        if (step < 63){
            const int tn = (step + 1) & 7;
#pragma unroll
            for (int t4 = 0; t4 < 4; ++t4)
#pragma unroll
                for (int q = 0; q < 4; ++q)
                    acc[t4][q] = X0[(bcb + g * 4 + q) * 4096 + tn * 512 + t4 * 128 + wid * 16 + r0];
        }
        // no trailing barrier: h1[p^1] write -> next phase-B read is fenced by
        // the next step's mid barrier; phase A touches only h0[p]/h0[p^1^1].
    }
}

// ---------- fused tail: conv1d(SAME,K=3) -> ssm -> outp(+resid xn) -> proj ----------
// grid 84, block 256 (4 waves). Each wave owns 16 rows end-to-end; LDS is only
// the per-wave C->A fragment transpose medium.
__global__ __launch_bounds__(256) void tail_k(
    const ushort_t* __restrict__ ls, const ushort_t* __restrict__ cWk,
    const float* __restrict__ cbias, const ushort_t* __restrict__ sW,
    const float* __restrict__ sbias, const ushort_t* __restrict__ oW,
    const float* __restrict__ obias, const float* __restrict__ xnF,
    const ushort_t* __restrict__ pW, const float* __restrict__ pbias,
    float* __restrict__ out)
{
    __shared__ ushort_t bufA[8192];
    __shared__ ushort_t bufB[8192];
    const int lane = threadIdx.x & 63, wave = threadIdx.x >> 6;
    const int r0 = lane & 15, g = lane >> 4;
    const int rowbase = blockIdx.x * 64;
    const int lr0 = wave * 16;

    // ---- conv ----
    {
        const int n = r0 & 7;
        bf16x8 a[3][4];
#pragma unroll
        for (int k = 0; k < 3; ++k){
            bool valid = (n + k >= 1) && (n + k <= 8);
            const ushort_t* ap = ls + (rowbase + lr0 + r0 + k - 1) * 128 + g * 8;
#pragma unroll
            for (int kt = 0; kt < 4; ++kt){
                bf16x8 z = {0,0,0,0,0,0,0,0};
                a[k][kt] = valid ? *(const bf16x8*)(ap + kt * 32) : z;
            }
        }
#pragma unroll
        for (int nt = 0; nt < 8; ++nt){
            const int col = nt * 16 + r0;
            float bv = cbias[col];
            f32x4 acc = {bv, bv, bv, bv};
#pragma unroll
            for (int k = 0; k < 3; ++k)
#pragma unroll
                for (int kt = 0; kt < 4; ++kt)
                    acc = __builtin_amdgcn_mfma_f32_16x16x32_bf16(
                            a[k][kt], *(const bf16x8*)(cWk + k * 16384 + col * 128 + kt * 32 + g * 8),
                            acc, 0, 0, 0);
#pragma unroll
            for (int q = 0; q < 4; ++q){
                int row = lr0 + g * 4 + q;
                bufA[row * 128 + (col ^ ((row & 7) << 3))] = f2b(acc[q]);
            }
        }
    }
    __syncthreads();
    // ---- ssm: bufA -> bufB ----
    {
        bf16x8 a[4];
#pragma unroll
        for (int kt = 0; kt < 4; ++kt)
            a[kt] = *(const bf16x8*)(&bufA[(lr0 + r0) * 128 + ((kt * 32 + g * 8) ^ ((r0 & 7) << 3))]);
#pragma unroll
        for (int nt = 0; nt < 8; ++nt){
            const int col = nt * 16 + r0;
            float bv = sbias[col];
            f32x4 acc = {bv, bv, bv, bv};
#pragma unroll
            for (int kt = 0; kt < 4; ++kt)
                acc = __builtin_amdgcn_mfma_f32_16x16x32_bf16(
                        a[kt], *(const bf16x8*)(sW + col * 128 + kt * 32 + g * 8), acc, 0, 0, 0);
#pragma unroll
            for (int q = 0; q < 4; ++q){
                int row = lr0 + g * 4 + q;
                bufB[row * 128 + (col ^ ((row & 7) << 3))] = f2b(acc[q]);
            }
        }
    }
    __syncthreads();
    // ---- outp + resid: bufB -> bufA ----
    {
        bf16x8 a[4];
#pragma unroll
        for (int kt = 0; kt < 4; ++kt)
            a[kt] = *(const bf16x8*)(&bufB[(lr0 + r0) * 128 + ((kt * 32 + g * 8) ^ ((r0 & 7) << 3))]);
#pragma unroll
        for (int nt = 0; nt < 8; ++nt){
            const int col = nt * 16 + r0;
            float bv = obias[col];
            f32x4 acc = {bv, bv, bv, bv};
#pragma unroll
            for (int kt = 0; kt < 4; ++kt)
                acc = __builtin_amdgcn_mfma_f32_16x16x32_bf16(
                        a[kt], *(const bf16x8*)(oW + col * 128 + kt * 32 + g * 8), acc, 0, 0, 0);
#pragma unroll
            for (int q = 0; q < 4; ++q){
                int row = lr0 + g * 4 + q;
                float v = acc[q] + xnF[(rowbase + row) * 128 + col];
                bufA[row * 128 + (col ^ ((row & 7) << 3))] = f2b(v);
            }
        }
    }
    __syncthreads();
    // ---- proj: bufA -> out (96 cols, f32) ----
    {
        bf16x8 a[4];
#pragma unroll
        for (int kt = 0; kt < 4; ++kt)
            a[kt] = *(const bf16x8*)(&bufA[(lr0 + r0) * 128 + ((kt * 32 + g * 8) ^ ((r0 & 7) << 3))]);
#pragma unroll
        for (int nt = 0; nt < 6; ++nt){
            const int col = nt * 16 + r0;
            float bv = pbias[col];
            f32x4 acc = {bv, bv, bv, bv};
#pragma unroll
            for (int kt = 0; kt < 4; ++kt)
                acc = __builtin_amdgcn_mfma_f32_16x16x32_bf16(
                        a[kt], *(const bf16x8*)(pW + col * 128 + kt * 32 + g * 8), acc, 0, 0, 0);
#pragma unroll
            for (int q = 0; q < 4; ++q)
                out[(rowbase + lr0 + g * 4 + q) * 96 + col] = acc[q];
        }
    }
}

// ---------- launch ----------
extern "C" void kernel_launch(void* const* d_in, const int* in_sizes, int n_in,
                              void* d_out, int out_size, void* d_ws, size_t ws_size,
                              hipStream_t stream)
{
    const float* x   = (const float*)d_in[0];
    const float* eW  = (const float*)d_in[1];
    const float* eb  = (const float*)d_in[2];
    const float* lng = (const float*)d_in[3];
    const float* lnb = (const float*)d_in[4];
    const float* vW  = (const float*)d_in[9];
    const float* vb  = (const float*)d_in[10];
    const float* Wx  = (const float*)d_in[11];
    const float* Wh  = (const float*)d_in[12];
    const float* lb  = (const float*)d_in[13];
    const float* cW  = (const float*)d_in[14];
    const float* cb_ = (const float*)d_in[15];
    const float* sW  = (const float*)d_in[16];
    const float* sb  = (const float*)d_in[17];
    const float* oW  = (const float*)d_in[18];
    const float* ob  = (const float*)d_in[19];
    const float* pW  = (const float*)d_in[20];
    const float* pb  = (const float*)d_in[21];

    char* ws = (char*)d_ws;
    float*    xnF = (float*)   (ws + 0);          // 5376x128 f32
    ushort_t* xnB = (ushort_t*)(ws + 2752512);    // 5376x128 bf16
    ushort_t* c0B = (ushort_t*)(ws + 4128768);    // ctx0 bf16
    float*    X0F = (float*)   (ws + 5505024);    // 5376x512 f32
    ushort_t* lsB = (ushort_t*)(ws + 16515072);   // lstm out bf16
    ushort_t* wb  = (ushort_t*)(ws + 22020096);   // bf16 weights

    prep_k<<<dim3(256, 9), 256, 0, stream>>>(vW, Wx, Wh, cW, sW, oW, pW, wb);
    embed_ln_k<<<672, 128, 0, stream>>>(x, eW, eb, lng, lnb, xnF, xnB);
    // ctx0 = xn @ vW^T + vb   (attention collapses to identity on v)
    mm16_k<<<84, 256, 0, stream>>>(xnB, wb + 0,      vb, nullptr, nullptr, c0B, 128);
    // X0 = ctx0 @ Wx0^T + b0
    mm16_k<<<84, 256, 0, stream>>>(c0B, wb + 16384,  lb, nullptr, X0F,     nullptr, 512);
    lstm_k<<<42, 512, 0, stream>>>(X0F, wb + 81920, wb + 147456, wb + 212992, lb, lsB);
    tail_k<<<84, 256, 0, stream>>>(lsB, wb + 278528, cb_, wb + 327680, sb,
                                   wb + 344064, ob, xnF, wb + 360448, pb, (float*)d_out);
}

// Round 3
// 253.820 us; speedup vs baseline: 1.3539x; 1.2003x over previous
//
#include <hip/hip_runtime.h>

typedef unsigned short ushort_t;
typedef unsigned int uint_t;

using bf16x8 = __attribute__((ext_vector_type(8))) short;
using f32x4  = __attribute__((ext_vector_type(4))) float;

// ---------- helpers ----------
__device__ __forceinline__ ushort_t f2b(float f){
    union { float f; uint_t u; } v; v.f = f;
    uint_t u = v.u;
    uint_t r = (u + 0x7FFFu + ((u >> 16) & 1u)) >> 16;   // RNE
    return (ushort_t)r;
}

// ---------- weight prep: f32 -> bf16 (+ conv restride) ----------
__global__ void prep_k(const float* __restrict__ vW, const float* __restrict__ Wx,
                       const float* __restrict__ Wh, const float* __restrict__ cW,
                       const float* __restrict__ sW, const float* __restrict__ oW,
                       const float* __restrict__ pW, ushort_t* __restrict__ wb)
{
    int idx = blockIdx.x * 256 + threadIdx.x;
    switch (blockIdx.y){
    case 0: if (idx < 16384) wb[idx]          = f2b(vW[idx]);           break;
    case 1: if (idx < 65536) wb[16384  + idx] = f2b(Wx[idx]);           break; // Wx0
    case 2: if (idx < 65536) wb[81920  + idx] = f2b(Wh[idx]);           break; // Wh0
    case 3: if (idx < 65536) wb[147456 + idx] = f2b(Wx[65536 + idx]);   break; // Wx1
    case 4: if (idx < 65536) wb[212992 + idx] = f2b(Wh[65536 + idx]);   break; // Wh1
    case 5: if (idx < 49152){                                                  // conv [k][o][i]
                int k = idx >> 14; int oi = idx & 16383;
                wb[278528 + idx] = f2b(cW[oi * 3 + k]);
            } break;
    case 6: if (idx < 16384) wb[327680 + idx] = f2b(sW[idx]);           break;
    case 7: if (idx < 16384) wb[344064 + idx] = f2b(oW[idx]);           break;
    case 8: if (idx < 12288) wb[360448 + idx] = f2b(pW[idx]);           break;
    }
}

// ---------- patch embed + layernorm ----------
__global__ void embed_ln_k(const float* __restrict__ x, const float* __restrict__ eW,
                           const float* __restrict__ eb, const float* __restrict__ lng,
                           const float* __restrict__ lnb,
                           float* __restrict__ xnF, ushort_t* __restrict__ xnB)
{
    const int e  = threadIdx.x;
    const int bc = blockIdx.x;
    const int b  = bc / 21, c = bc % 21;
    const int wid = threadIdx.x >> 6;

    float w[16];
#pragma unroll
    for (int p = 0; p < 16; ++p) w[p] = eW[e * 16 + p];
    const float bias = eb[e], gam = lng[e], bet = lnb[e];

    __shared__ float patch[16];
    __shared__ float red[4];

    for (int n = 0; n < 8; ++n){
        if (e < 16) patch[e] = x[(b * 128 + n * 16 + e) * 21 + c];
        __syncthreads();
        float v = bias;
#pragma unroll
        for (int p = 0; p < 16; ++p) v += w[p] * patch[p];

        float s = v, sq = v * v;
#pragma unroll
        for (int m = 32; m >= 1; m >>= 1){
            s  += __shfl_xor(s,  m);
            sq += __shfl_xor(sq, m);
        }
        if ((threadIdx.x & 63) == 0){ red[wid] = s; red[2 + wid] = sq; }
        __syncthreads();
        float S  = red[0] + red[1];
        float SQ = red[2] + red[3];
        float mean = S * (1.f / 128.f);
        float var  = SQ * (1.f / 128.f) - mean * mean;
        float r    = rsqrtf(var + 1e-5f);
        float y    = (v - mean) * r * gam + bet;
        int row = bc * 8 + n;
        xnF[row * 128 + e] = y;
        xnB[row * 128 + e] = f2b(y);
        __syncthreads();
    }
}

// ---------- generic MFMA matmul: Y(5376 x OUT) = A(5376x128) @ W(OUTx128)^T + bias ----------
__global__ void mm16_k(const ushort_t* __restrict__ A, const ushort_t* __restrict__ W,
                       const float* __restrict__ bias, const float* __restrict__ resid,
                       float* __restrict__ outF, ushort_t* __restrict__ outB, int OUT)
{
    const int lane = threadIdx.x & 63, wave = threadIdx.x >> 6;
    const int rowbase = blockIdx.x * 64 + wave * 16;
    const int r0 = lane & 15, g = lane >> 4;

    bf16x8 a[4];
    const ushort_t* ap = A + (rowbase + r0) * 128 + g * 8;
#pragma unroll
    for (int kt = 0; kt < 4; ++kt) a[kt] = *(const bf16x8*)(ap + kt * 32);

    const int ntiles = OUT >> 4;
    for (int nt = 0; nt < ntiles; ++nt){
        const int col = nt * 16 + r0;
        float bv = bias[col];
        f32x4 acc = {bv, bv, bv, bv};
        const ushort_t* wp = W + col * 128 + g * 8;
#pragma unroll
        for (int kt = 0; kt < 4; ++kt)
            acc = __builtin_amdgcn_mfma_f32_16x16x32_bf16(a[kt], *(const bf16x8*)(wp + kt * 32), acc, 0, 0, 0);
#pragma unroll
        for (int q = 0; q < 4; ++q){
            int row = rowbase + g * 4 + q;
            float val = acc[q];
            if (resid) val += resid[row * 128 + col];
            if (outF)  outF[row * OUT + col] = val;
            if (outB)  outB[row * OUT + col] = f2b(val);
        }
    }
}

// ---------- persistent 2-layer LSTM, layer-pipelined ----------
// grid 42, block 512 (8 waves, 2/SIMD). 16 batch rows per block.
// Phase ph (0..64): L0(t=ph) [ph<64]  CONCURRENT WITH  L1(t=ph-1) [ph>0].
// Wh0,Wh1 resident in registers (128, AGPR-able); Wx1 in LDS (swizzled).
// One barrier per phase. X0 prefetched into dead accA a full phase early.
__global__ __launch_bounds__(512, 2) void lstm_k(
    const float* __restrict__ X0, const ushort_t* __restrict__ Wh0,
    const ushort_t* __restrict__ Wx1, const ushort_t* __restrict__ Wh1,
    const float* __restrict__ lb, ushort_t* __restrict__ outB)
{
    extern __shared__ ushort_t smem[];
    ushort_t* h0  = smem;            // [2][2048]
    ushort_t* h1  = smem + 4096;     // [2][2048]
    ushort_t* wxs = smem + 8192;     // 512 cols x 128, 16B-chunk swizzled

    const int tid  = threadIdx.x;
    const int wid  = tid >> 6, lane = tid & 63;
    const int r0   = lane & 15, g = lane >> 4;
    const int sw   = r0 & 7;
    const int bcb  = blockIdx.x * 16;
    const float K1 = 1.44269504f, K2 = 2.88539008f;

    for (int i = tid; i < 2048; i += 512){
        h0[i] = 0; h0[2048 + i] = 0; h1[i] = 0; h1[2048 + i] = 0;
    }
    // stage Wx1 -> LDS, swizzled in 16B chunks: chunk e0 of col -> slot e0^(col&7)
    for (int idx = tid; idx < 8192; idx += 512){
        int col = idx >> 4, e0 = idx & 15;
        *(bf16x8*)(wxs + col * 128 + ((e0 ^ (col & 7)) << 3)) =
            *(const bf16x8*)(Wx1 + col * 128 + e0 * 8);
    }

    bf16x8 wh0[4][4], wh1[4][4];
#pragma unroll
    for (int t4 = 0; t4 < 4; ++t4){
        const int cb = t4 * 128 + wid * 16;
#pragma unroll
        for (int kt = 0; kt < 4; ++kt){
            wh0[t4][kt] = *(const bf16x8*)(Wh0 + (cb + r0) * 128 + kt * 32 + g * 8);
            wh1[t4][kt] = *(const bf16x8*)(Wh1 + (cb + r0) * 128 + kt * 32 + g * 8);
        }
    }
    float b1v[4];
#pragma unroll
    for (int t4 = 0; t4 < 4; ++t4) b1v[t4] = lb[512 + t4 * 128 + wid * 16 + r0];

    float c0[4] = {0,0,0,0}, c1[4] = {0,0,0,0};

    // accA pre-loaded with X0 slice for t=0 (contains Wx0@ctx + b0)
    f32x4 accA[4];
#pragma unroll
    for (int t4 = 0; t4 < 4; ++t4)
#pragma unroll
        for (int q = 0; q < 4; ++q)
            accA[t4][q] = X0[(bcb + g * 4 + q) * 4096 + t4 * 128 + wid * 16 + r0];

    __syncthreads();

    for (int ph = 0; ph <= 64; ++ph){
        const int rb = (ph + 1) & 1;     // buffers written in phase ph-1
        const int wbuf = ph & 1;

        // shared fragments: a0 = h0(ph-1) (L0 state input AND L1 x input); ah = h1(ph-2)
        bf16x8 a0[4], ah[4];
#pragma unroll
        for (int kt = 0; kt < 4; ++kt){
            const int off = (kt * 32 + g * 8) ^ (sw << 3);
            a0[kt] = *(const bf16x8*)(&h0[rb * 2048 + r0 * 128 + off]);
            ah[kt] = *(const bf16x8*)(&h1[rb * 2048 + r0 * 128 + off]);
        }

        // ---- L0 MFMAs (t = ph) ----
        if (ph < 64){
#pragma unroll
            for (int kt = 0; kt < 4; ++kt)
#pragma unroll
                for (int t4 = 0; t4 < 4; ++t4)
                    accA[t4] = __builtin_amdgcn_mfma_f32_16x16x32_bf16(a0[kt], wh0[t4][kt], accA[t4], 0, 0, 0);
        }

        // ---- L1 MFMAs (t = ph-1) ----
        f32x4 accB[4];
        if (ph > 0){
#pragma unroll
            for (int t4 = 0; t4 < 4; ++t4){
                f32x4 tmp = {b1v[t4], b1v[t4], b1v[t4], b1v[t4]};
                accB[t4] = tmp;
            }
#pragma unroll
            for (int kt = 0; kt < 4; ++kt){
#pragma unroll
                for (int t4 = 0; t4 < 4; ++t4){
                    bf16x8 wx = *(const bf16x8*)(wxs + (t4 * 128 + wid * 16 + r0) * 128
                                                 + (((kt * 4 + g) ^ sw) << 3));
                    accB[t4] = __builtin_amdgcn_mfma_f32_16x16x32_bf16(a0[kt], wx,          accB[t4], 0, 0, 0);
                    accB[t4] = __builtin_amdgcn_mfma_f32_16x16x32_bf16(ah[kt], wh1[t4][kt], accB[t4], 0, 0, 0);
                }
            }
        }

        // ---- EW layer 0 -> h0[wbuf]; then recycle accA as X0 prefetch target ----
        if (ph < 64){
#pragma unroll
            for (int q = 0; q < 4; ++q){
                float iv = accA[0][q], fv = accA[1][q], gv = accA[2][q], ov = accA[3][q];
                float af = 1.f + __builtin_amdgcn_exp2f(-K1 * fv);
                float ai = 1.f + __builtin_amdgcn_exp2f(-K1 * iv);
                float bg = 1.f + __builtin_amdgcn_exp2f( K2 * gv);
                float cn = c0[q] * __builtin_amdgcn_rcpf(af)
                         + (bg - 2.f) * __builtin_amdgcn_rcpf(ai * bg);
                c0[q] = cn;
                float ao = 1.f + __builtin_amdgcn_exp2f(-K1 * ov);
                float bc = 1.f + __builtin_amdgcn_exp2f( K2 * cn);
                float hv = (bc - 2.f) * __builtin_amdgcn_rcpf(ao * bc);
                int row = g * 4 + q;
                h0[wbuf * 2048 + row * 128 + ((wid * 16 + r0) ^ ((row & 7) << 3))] = f2b(hv);
            }
            if (ph < 63){
                const int tn = (ph + 1) & 7;
#pragma unroll
                for (int t4 = 0; t4 < 4; ++t4)
#pragma unroll
                    for (int q = 0; q < 4; ++q)
                        accA[t4][q] = X0[(bcb + g * 4 + q) * 4096 + tn * 512 + t4 * 128 + wid * 16 + r0];
            }
        }

        // ---- EW layer 1 -> h1[wbuf] (+ output for t >= 56) ----
        if (ph > 0){
#pragma unroll
            for (int q = 0; q < 4; ++q){
                float iv = accB[0][q], fv = accB[1][q], gv = accB[2][q], ov = accB[3][q];
                float af = 1.f + __builtin_amdgcn_exp2f(-K1 * fv);
                float ai = 1.f + __builtin_amdgcn_exp2f(-K1 * iv);
                float bg = 1.f + __builtin_amdgcn_exp2f( K2 * gv);
                float cn = c1[q] * __builtin_amdgcn_rcpf(af)
                         + (bg - 2.f) * __builtin_amdgcn_rcpf(ai * bg);
                c1[q] = cn;
                float ao = 1.f + __builtin_amdgcn_exp2f(-K1 * ov);
                float bc = 1.f + __builtin_amdgcn_exp2f( K2 * cn);
                float hv = (bc - 2.f) * __builtin_amdgcn_rcpf(ao * bc);
                int row = g * 4 + q;
                h1[wbuf * 2048 + row * 128 + ((wid * 16 + r0) ^ ((row & 7) << 3))] = f2b(hv);
                if (ph >= 57)
                    outB[((bcb + row) * 8 + ((ph - 1) & 7)) * 128 + wid * 16 + r0] = f2b(hv);
            }
        }
        __syncthreads();
    }
}

// ---------- fused tail: conv1d(SAME,K=3) -> ssm -> outp(+resid xn) -> proj ----------
__global__ __launch_bounds__(256) void tail_k(
    const ushort_t* __restrict__ ls, const ushort_t* __restrict__ cWk,
    const float* __restrict__ cbias, const ushort_t* __restrict__ sW,
    const float* __restrict__ sbias, const ushort_t* __restrict__ oW,
    const float* __restrict__ obias, const float* __restrict__ xnF,
    const ushort_t* __restrict__ pW, const float* __restrict__ pbias,
    float* __restrict__ out)
{
    __shared__ ushort_t bufA[8192];
    __shared__ ushort_t bufB[8192];
    const int lane = threadIdx.x & 63, wave = threadIdx.x >> 6;
    const int r0 = lane & 15, g = lane >> 4;
    const int rowbase = blockIdx.x * 64;
    const int lr0 = wave * 16;

    // ---- conv ----
    {
        const int n = r0 & 7;
        bf16x8 a[3][4];
#pragma unroll
        for (int k = 0; k < 3; ++k){
            bool valid = (n + k >= 1) && (n + k <= 8);
            const ushort_t* ap = ls + (rowbase + lr0 + r0 + k - 1) * 128 + g * 8;
#pragma unroll
            for (int kt = 0; kt < 4; ++kt){
                bf16x8 z = {0,0,0,0,0,0,0,0};
                a[k][kt] = valid ? *(const bf16x8*)(ap + kt * 32) : z;
            }
        }
#pragma unroll
        for (int nt = 0; nt < 8; ++nt){
            const int col = nt * 16 + r0;
            float bv = cbias[col];
            f32x4 acc = {bv, bv, bv, bv};
#pragma unroll
            for (int k = 0; k < 3; ++k)
#pragma unroll
                for (int kt = 0; kt < 4; ++kt)
                    acc = __builtin_amdgcn_mfma_f32_16x16x32_bf16(
                            a[k][kt], *(const bf16x8*)(cWk + k * 16384 + col * 128 + kt * 32 + g * 8),
                            acc, 0, 0, 0);
#pragma unroll
            for (int q = 0; q < 4; ++q){
                int row = lr0 + g * 4 + q;
                bufA[row * 128 + (col ^ ((row & 7) << 3))] = f2b(acc[q]);
            }
        }
    }
    __syncthreads();
    // ---- ssm: bufA -> bufB ----
    {
        bf16x8 a[4];
#pragma unroll
        for (int kt = 0; kt < 4; ++kt)
            a[kt] = *(const bf16x8*)(&bufA[(lr0 + r0) * 128 + ((kt * 32 + g * 8) ^ ((r0 & 7) << 3))]);
#pragma unroll
        for (int nt = 0; nt < 8; ++nt){
            const int col = nt * 16 + r0;
            float bv = sbias[col];
            f32x4 acc = {bv, bv, bv, bv};
#pragma unroll
            for (int kt = 0; kt < 4; ++kt)
                acc = __builtin_amdgcn_mfma_f32_16x16x32_bf16(
                        a[kt], *(const bf16x8*)(sW + col * 128 + kt * 32 + g * 8), acc, 0, 0, 0);
#pragma unroll
            for (int q = 0; q < 4; ++q){
                int row = lr0 + g * 4 + q;
                bufB[row * 128 + (col ^ ((row & 7) << 3))] = f2b(acc[q]);
            }
        }
    }
    __syncthreads();
    // ---- outp + resid: bufB -> bufA ----
    {
        bf16x8 a[4];
#pragma unroll
        for (int kt = 0; kt < 4; ++kt)
            a[kt] = *(const bf16x8*)(&bufB[(lr0 + r0) * 128 + ((kt * 32 + g * 8) ^ ((r0 & 7) << 3))]);
#pragma unroll
        for (int nt = 0; nt < 8; ++nt){
            const int col = nt * 16 + r0;
            float bv = obias[col];
            f32x4 acc = {bv, bv, bv, bv};
#pragma unroll
            for (int kt = 0; kt < 4; ++kt)
                acc = __builtin_amdgcn_mfma_f32_16x16x32_bf16(
                        a[kt], *(const bf16x8*)(oW + col * 128 + kt * 32 + g * 8), acc, 0, 0, 0);
#pragma unroll
            for (int q = 0; q < 4; ++q){
                int row = lr0 + g * 4 + q;
                float v = acc[q] + xnF[(rowbase + row) * 128 + col];
                bufA[row * 128 + (col ^ ((row & 7) << 3))] = f2b(v);
            }
        }
    }
    __syncthreads();
    // ---- proj: bufA -> out (96 cols, f32) ----
    {
        bf16x8 a[4];
#pragma unroll
        for (int kt = 0; kt < 4; ++kt)
            a[kt] = *(const bf16x8*)(&bufA[(lr0 + r0) * 128 + ((kt * 32 + g * 8) ^ ((r0 & 7) << 3))]);
#pragma unroll
        for (int nt = 0; nt < 6; ++nt){
            const int col = nt * 16 + r0;
            float bv = pbias[col];
            f32x4 acc = {bv, bv, bv, bv};
#pragma unroll
            for (int kt = 0; kt < 4; ++kt)
                acc = __builtin_amdgcn_mfma_f32_16x16x32_bf16(
                        a[kt], *(const bf16x8*)(pW + col * 128 + kt * 32 + g * 8), acc, 0, 0, 0);
#pragma unroll
            for (int q = 0; q < 4; ++q)
                out[(rowbase + lr0 + g * 4 + q) * 96 + col] = acc[q];
        }
    }
}

// ---------- launch ----------
extern "C" void kernel_launch(void* const* d_in, const int* in_sizes, int n_in,
                              void* d_out, int out_size, void* d_ws, size_t ws_size,
                              hipStream_t stream)
{
    const float* x   = (const float*)d_in[0];
    const float* eW  = (const float*)d_in[1];
    const float* eb  = (const float*)d_in[2];
    const float* lng = (const float*)d_in[3];
    const float* lnb = (const float*)d_in[4];
    const float* vW  = (const float*)d_in[9];
    const float* vb  = (const float*)d_in[10];
    const float* Wx  = (const float*)d_in[11];
    const float* Wh  = (const float*)d_in[12];
    const float* lb  = (const float*)d_in[13];
    const float* cW  = (const float*)d_in[14];
    const float* cb_ = (const float*)d_in[15];
    const float* sW  = (const float*)d_in[16];
    const float* sb  = (const float*)d_in[17];
    const float* oW  = (const float*)d_in[18];
    const float* ob  = (const float*)d_in[19];
    const float* pW  = (const float*)d_in[20];
    const float* pb  = (const float*)d_in[21];

    char* ws = (char*)d_ws;
    float*    xnF = (float*)   (ws + 0);          // 5376x128 f32
    ushort_t* xnB = (ushort_t*)(ws + 2752512);    // 5376x128 bf16
    ushort_t* c0B = (ushort_t*)(ws + 4128768);    // ctx0 bf16
    float*    X0F = (float*)   (ws + 5505024);    // 5376x512 f32
    ushort_t* lsB = (ushort_t*)(ws + 16515072);   // lstm out bf16
    ushort_t* wb  = (ushort_t*)(ws + 22020096);   // bf16 weights

    static int lds_set = 0;
    if (!lds_set){
        hipFuncSetAttribute((const void*)lstm_k,
                            hipFuncAttributeMaxDynamicSharedMemorySize, 147456);
        lds_set = 1;
    }

    prep_k<<<dim3(256, 9), 256, 0, stream>>>(vW, Wx, Wh, cW, sW, oW, pW, wb);
    embed_ln_k<<<672, 128, 0, stream>>>(x, eW, eb, lng, lnb, xnF, xnB);
    // ctx0 = xn @ vW^T + vb   (attention collapses to identity on v)
    mm16_k<<<84, 256, 0, stream>>>(xnB, wb + 0,      vb, nullptr, nullptr, c0B, 128);
    // X0 = ctx0 @ Wx0^T + b0
    mm16_k<<<84, 256, 0, stream>>>(c0B, wb + 16384,  lb, nullptr, X0F,     nullptr, 512);
    lstm_k<<<42, 512, 147456, stream>>>(X0F, wb + 81920, wb + 147456, wb + 212992, lb, lsB);
    tail_k<<<84, 256, 0, stream>>>(lsB, wb + 278528, cb_, wb + 327680, sb,
                                   wb + 344064, ob, xnF, wb + 360448, pb, (float*)d_out);
}